// Round 1
// baseline (632.546 us; speedup 1.0000x reference)
//
#include <hip/hip_runtime.h>
#include <hip/hip_bf16.h>
#include <stdint.h>

typedef unsigned short u16;
typedef short s16x8 __attribute__((ext_vector_type(8)));
typedef float f32x4 __attribute__((ext_vector_type(4)));
typedef unsigned short u16x4 __attribute__((ext_vector_type(4)));

#define GLL(gp, lp) __builtin_amdgcn_global_load_lds( \
    (const __attribute__((address_space(1))) void*)(gp), \
    (__attribute__((address_space(3))) void*)(lp), 16, 0, 0)

// ---------------- exact-math helpers (match XLA CPU f32 semantics) ----------

__device__ __forceinline__ float xla_erf(float x) {
#pragma clang fp contract(off)
  // XLA EmitErfF32 / Eigen rational interpolant, clamp to +-kErfInvOneMinusHalfULP
  x = fminf(3.832506856900711f, fmaxf(-3.832506856900711f, x));
  float x2 = x * x;
  float p = -2.72614225801306e-10f;
  p = p * x2 + 2.77068142495902e-08f;
  p = p * x2 + -2.10102402082508e-06f;
  p = p * x2 + -5.69250639462346e-05f;
  p = p * x2 + -7.34990630326855e-04f;
  p = p * x2 + -2.95459980854025e-03f;
  p = p * x2 + -1.60960333262415e-02f;
  p = x * p;
  float q = -1.45660718464996e-05f;
  q = q * x2 + -2.13374055278905e-04f;
  q = q * x2 + -1.68282697438203e-03f;
  q = q * x2 + -7.37332916720468e-03f;
  q = q * x2 + -1.42647390514189e-02f;
  return p / q;
}

__device__ __forceinline__ float gelu_exact(float x) {
#pragma clang fp contract(off)
  float t = x / 1.41421356237309504880f;  // np.sqrt(2) as f32
  float e = xla_erf(t);
  float u = e + 1.0f;
  float v = x * u;
  return v * 0.5f;  // /2 exact
}

__device__ __forceinline__ float epi_scale(float iacc, float sc, float b) {
#pragma clang fp contract(off)
  float v = iacc * sc;  // cim * (sx*sw)
  v = v + b;            // + bias
  return v;
}

__device__ __forceinline__ int quant1(float x, float scale) {
#pragma clang fp contract(off)
  float t = x / scale;                  // IEEE div
  t = rintf(t);                         // round half-to-even == jnp.round
  t = fmaxf(-8.0f, fminf(7.0f, t));     // clip(-(qmax+1), qmax)
  return (int)t;
}

// ---------------- kernels ---------------------------------------------------

__global__ void init_kernel(unsigned* slots) {
  if (threadIdx.x < 4) slots[threadIdx.x] = 0u;
}

__global__ void absmax_kernel(const float* __restrict__ in, long n4, unsigned* slot) {
  float m = 0.0f;
  long i = (long)blockIdx.x * blockDim.x + threadIdx.x;
  long stride = (long)gridDim.x * blockDim.x;
  const float4* p = (const float4*)in;
  for (; i < n4; i += stride) {
    float4 v = p[i];
    m = fmaxf(m, fmaxf(fmaxf(fabsf(v.x), fabsf(v.y)), fmaxf(fabsf(v.z), fabsf(v.w))));
  }
  for (int o = 32; o > 0; o >>= 1) m = fmaxf(m, __shfl_xor(m, o));
  if ((threadIdx.x & 63) == 0) atomicMax(slot, __float_as_uint(m));
}

// input fp32 [R][C] row-major, C % 256 == 0. Writes bf16 quantized [Rpad][C]
// (zeros for padded rows) and per-(row,segment) signed AND-mask value.
__global__ void quant_kernel(const float* __restrict__ in, int R, int C,
                             const unsigned* __restrict__ slot,
                             u16* __restrict__ qout, float* __restrict__ sval) {
  const int segs_per_row = C >> 8;
  const int seg = blockIdx.x * 4 + (threadIdx.x >> 6);  // one wave per 256-elem segment
  const int lane = threadIdx.x & 63;
  const int r = seg / segs_per_row;
  const int s = seg - r * segs_per_row;
  const float scale = fmaxf(__uint_as_float(*slot) / 7.0f, 1e-8f);
  const size_t base = (size_t)r * C + (size_t)s * 256 + lane * 4;
  int mask = 0;
  if (r < R) {
    float4 v = *(const float4*)(in + base);
    int q0 = quant1(v.x, scale);
    int q1 = quant1(v.y, scale);
    int q2 = quant1(v.z, scale);
    int q3 = quant1(v.w, scale);
    u16x4 o;
    o[0] = (u16)(__float_as_uint((float)q0) >> 16);  // small ints: truncation exact
    o[1] = (u16)(__float_as_uint((float)q1) >> 16);
    o[2] = (u16)(__float_as_uint((float)q2) >> 16);
    o[3] = (u16)(__float_as_uint((float)q3) >> 16);
    *(u16x4*)(qout + base) = o;
    mask = q0 & q1 & q2 & q3 & 15;  // AND of two's-complement nibbles
  } else {
    u16x4 z = {0, 0, 0, 0};
    *(u16x4*)(qout + base) = z;
    mask = 0;
  }
  for (int o = 32; o > 0; o >>= 1) mask &= __shfl_xor(mask, o);
  if (lane == 0) sval[(size_t)r * segs_per_row + s] = (float)((mask & 7) - (mask & 8));
}

// C[m][n] = (sum_k A[m][k]*B[n][k] - sum_s svalA[m][s]*svalB[n][s]) * (sa*sb) + bias[n]
// A: [Mpad][K] bf16 (quantized ints), B: [N][K] bf16. 128x128 tile, 4 waves,
// 16x16x32 bf16 MFMA (exact integer arithmetic), global_load_lds staging.
__global__ __launch_bounds__(256) void gemm_cim(
    const u16* __restrict__ A, const u16* __restrict__ B,
    int Mstore, int K, int mtiles,
    const float* __restrict__ svalA, const float* __restrict__ svalB, int nseg,
    const unsigned* __restrict__ slots, int slotA, int slotB,
    const float* __restrict__ bias,
    float* __restrict__ out, int ldo, int do_gelu) {
  __shared__ u16 As[128 * 32];
  __shared__ u16 Bs[128 * 32];
  const int tid = threadIdx.x;
  const int lane = tid & 63;
  const int wv = tid >> 6;
  const int bm = blockIdx.x % mtiles;
  const int bn = blockIdx.x / mtiles;
  const long m0 = (long)bm * 128;
  const long n0 = (long)bn * 128;

  // staging geometry: per issue, 256 threads x 16B = 4KB = 64 rows of 64B
  const int off = wv * 1024 + lane * 16;  // byte offset inside 4KB chunk
  const int r0 = off >> 6;                // row 0..63
  const int cb = off & 63;                // byte within 64B (32 bf16) k-slice
  const char* gA0 = (const char*)A + ((m0 + r0) * (long)K) * 2 + cb;
  const char* gA1 = gA0 + 64L * (long)K * 2;
  const char* gB0 = (const char*)B + ((n0 + r0) * (long)K) * 2 + cb;
  const char* gB1 = gB0 + 64L * (long)K * 2;
  char* lA = (char*)As + (size_t)wv * 1024;  // wave-uniform LDS dest base
  char* lB = (char*)Bs + (size_t)wv * 1024;

  const int wm = wv >> 1, wn = wv & 1;    // 2x2 waves, 64x64 per wave
  const int lr = lane & 15, kg = lane >> 4;

  f32x4 acc[4][4] = {};

  const int nk = K >> 5;
  for (int kt = 0; kt < nk; ++kt) {
    const long kb = (long)kt * 64;
    __syncthreads();  // prev iter's LDS reads done
    GLL(gA0 + kb, lA);
    GLL(gA1 + kb, lA + 4096);
    GLL(gB0 + kb, lB);
    GLL(gB1 + kb, lB + 4096);
    __syncthreads();  // vmcnt drained before barrier -> LDS tile ready
    s16x8 av[4], bv[4];
#pragma unroll
    for (int f = 0; f < 4; ++f)
      av[f] = *(const s16x8*)(As + (wm * 64 + f * 16 + lr) * 32 + kg * 8);
#pragma unroll
    for (int f = 0; f < 4; ++f)
      bv[f] = *(const s16x8*)(Bs + (wn * 64 + f * 16 + lr) * 32 + kg * 8);
#pragma unroll
    for (int fa = 0; fa < 4; ++fa)
#pragma unroll
      for (int fb = 0; fb < 4; ++fb)
        acc[fa][fb] = __builtin_amdgcn_mfma_f32_16x16x32_bf16(av[fa], bv[fb], acc[fa][fb], 0, 0, 0);
  }

  // epilogue
  const float sa = fmaxf(__uint_as_float(slots[slotA]) / 7.0f, 1e-8f);
  const float sb = fmaxf(__uint_as_float(slots[slotB]) / 7.0f, 1e-8f);
  const float sc = sa * sb;
#pragma unroll
  for (int fa = 0; fa < 4; ++fa) {
#pragma unroll
    for (int r = 0; r < 4; ++r) {
      const long m = m0 + wm * 64 + fa * 16 + kg * 4 + r;  // C/D: row=(lane>>4)*4+reg
      if (m < Mstore) {
#pragma unroll
        for (int fb = 0; fb < 4; ++fb) {
          const long n = n0 + wn * 64 + fb * 16 + lr;      // C/D: col=lane&15
          float corr = 0.0f;
          for (int s = 0; s < nseg; ++s)
            corr += svalA[m * nseg + s] * svalB[n * nseg + s];  // exact small ints
          float iacc = acc[fa][fb][r] - corr;  // exact integer in f32
          float v = epi_scale(iacc, sc, bias[n]);
          if (do_gelu) v = gelu_exact(v);
          out[m * (long)ldo + n] = v;
        }
      }
    }
  }
}

// ---------------- launch -----------------------------------------------------

extern "C" void kernel_launch(void* const* d_in, const int* in_sizes, int n_in,
                              void* d_out, int out_size, void* d_ws, size_t ws_size,
                              hipStream_t stream) {
  const float* x  = (const float*)d_in[0];
  const float* w1 = (const float*)d_in[1];
  const float* b1 = (const float*)d_in[2];
  const float* w2 = (const float*)d_in[3];
  const float* b2 = (const float*)d_in[4];
  float* out = (float*)d_out;

  const int Ntok = 16 * 197;  // 3152
  const int Mpad = 3200;      // 25 tiles of 128
  const int D = 768, H = 3072;

  char* ws = (char*)d_ws;
  size_t o = 0;
  unsigned* slots = (unsigned*)(ws + o); o += 256;             // [x, w1, w2, h]
  u16* xq   = (u16*)(ws + o); o += (size_t)Mpad * D * 2;
  u16* wq1  = (u16*)(ws + o); o += (size_t)H * D * 2;
  u16* wq2  = (u16*)(ws + o); o += (size_t)D * H * 2;
  u16* hq   = (u16*)(ws + o); o += (size_t)Mpad * H * 2;
  float* hbuf = (float*)(ws + o); o += (size_t)Ntok * H * 4;
  float* svalX1 = (float*)(ws + o); o += (size_t)Mpad * 3 * 4;
  float* svalW1 = (float*)(ws + o); o += (size_t)H * 3 * 4;
  float* svalX2 = (float*)(ws + o); o += (size_t)Mpad * 12 * 4;
  float* svalW2 = (float*)(ws + o); o += (size_t)D * 12 * 4;
  (void)ws_size; (void)in_sizes; (void)n_in; (void)out_size;

  hipLaunchKernelGGL(init_kernel, dim3(1), dim3(64), 0, stream, slots);

  hipLaunchKernelGGL(absmax_kernel, dim3(2048), dim3(256), 0, stream,
                     x, (long)Ntok * D / 4, slots + 0);
  hipLaunchKernelGGL(absmax_kernel, dim3(2048), dim3(256), 0, stream,
                     w1, (long)H * D / 4, slots + 1);
  hipLaunchKernelGGL(absmax_kernel, dim3(2048), dim3(256), 0, stream,
                     w2, (long)D * H / 4, slots + 2);

  hipLaunchKernelGGL(quant_kernel, dim3(Mpad * (D / 256) / 4), dim3(256), 0, stream,
                     x, Ntok, D, slots + 0, xq, svalX1);
  hipLaunchKernelGGL(quant_kernel, dim3(H * (D / 256) / 4), dim3(256), 0, stream,
                     w1, H, D, slots + 1, wq1, svalW1);
  hipLaunchKernelGGL(quant_kernel, dim3(D * (H / 256) / 4), dim3(256), 0, stream,
                     w2, D, H, slots + 2, wq2, svalW2);

  // layer 1: h = gelu(cim(x,w1) + b1)
  hipLaunchKernelGGL(gemm_cim, dim3((Mpad / 128) * (H / 128)), dim3(256), 0, stream,
                     xq, wq1, Ntok, D, Mpad / 128,
                     svalX1, svalW1, 3, slots, 0, 1, b1, hbuf, H, 1);

  hipLaunchKernelGGL(absmax_kernel, dim3(2048), dim3(256), 0, stream,
                     hbuf, (long)Ntok * H / 4, slots + 3);
  hipLaunchKernelGGL(quant_kernel, dim3(Mpad * (H / 256) / 4), dim3(256), 0, stream,
                     hbuf, Ntok, H, slots + 3, hq, svalX2);

  // layer 2: out = cim(h,w2) + b2
  hipLaunchKernelGGL(gemm_cim, dim3((Mpad / 128) * (D / 128)), dim3(256), 0, stream,
                     hq, wq2, Ntok, H, Mpad / 128,
                     svalX2, svalW2, 12, slots, 3, 2, b2, out, D, 0);
}

// Round 2
// 231.821 us; speedup vs baseline: 2.7286x; 2.7286x over previous
//
#include <hip/hip_runtime.h>
#include <hip/hip_bf16.h>
#include <stdint.h>

typedef unsigned short u16;
typedef short s16x8 __attribute__((ext_vector_type(8)));
typedef float f32x4 __attribute__((ext_vector_type(4)));
typedef unsigned short u16x4 __attribute__((ext_vector_type(4)));

#define GLL(gp, lp) __builtin_amdgcn_global_load_lds( \
    (const __attribute__((address_space(1))) void*)(gp), \
    (__attribute__((address_space(3))) void*)(lp), 16, 0, 0)

// ---------------- exact-math helpers (match XLA/np f32 semantics) -----------

__device__ __forceinline__ float xla_erf(float x) {
#pragma clang fp contract(off)
  x = fminf(3.832506856900711f, fmaxf(-3.832506856900711f, x));
  float x2 = x * x;
  float p = -2.72614225801306e-10f;
  p = p * x2 + 2.77068142495902e-08f;
  p = p * x2 + -2.10102402082508e-06f;
  p = p * x2 + -5.69250639462346e-05f;
  p = p * x2 + -7.34990630326855e-04f;
  p = p * x2 + -2.95459980854025e-03f;
  p = p * x2 + -1.60960333262415e-02f;
  p = x * p;
  float q = -1.45660718464996e-05f;
  q = q * x2 + -2.13374055278905e-04f;
  q = q * x2 + -1.68282697438203e-03f;
  q = q * x2 + -7.37332916720468e-03f;
  q = q * x2 + -1.42647390514189e-02f;
  return p / q;
}

__device__ __forceinline__ float gelu_exact(float x) {
#pragma clang fp contract(off)
  float t = x / 1.41421356237309504880f;
  float e = xla_erf(t);
  float u = e + 1.0f;
  float v = x * u;
  return v * 0.5f;
}

__device__ __forceinline__ float epi_scale(float iacc, float sc, float b) {
#pragma clang fp contract(off)
  float v = iacc * sc;
  v = v + b;
  return v;
}

__device__ __forceinline__ int quant1(float x, float scale) {
#pragma clang fp contract(off)
  float t = x / scale;
  t = rintf(t);
  t = fmaxf(-8.0f, fminf(7.0f, t));
  return (int)t;
}

// ---------------- small kernels ---------------------------------------------

__global__ void init_kernel(unsigned* slots) {
  if (threadIdx.x < 4) slots[threadIdx.x] = 0u;
}

// one dispatch, blockIdx.y selects tensor {x, w1, w2}
__global__ void absmax3(const float* __restrict__ p0, long n0,
                        const float* __restrict__ p1, long n1,
                        const float* __restrict__ p2, long n2,
                        unsigned* __restrict__ slots) {
  const int t = blockIdx.y;
  const float4* p = (const float4*)(t == 0 ? p0 : (t == 1 ? p1 : p2));
  const long n4 = (t == 0 ? n0 : (t == 1 ? n1 : n2));
  float m = 0.0f;
  long i = (long)blockIdx.x * blockDim.x + threadIdx.x;
  const long stride = (long)gridDim.x * blockDim.x;
  for (; i < n4; i += stride) {
    float4 v = p[i];
    m = fmaxf(m, fmaxf(fmaxf(fabsf(v.x), fabsf(v.y)), fmaxf(fabsf(v.z), fabsf(v.w))));
  }
  for (int o = 32; o > 0; o >>= 1) m = fmaxf(m, __shfl_xor(m, o));
  if ((threadIdx.x & 63) == 0) atomicMax(slots + t, __float_as_uint(m));
}

// fp32 [R][C] -> bf16-int [Rpad][ldq] with ldq = C + 32; the 32 extra columns
// hold the per-segment signed AND-mask value (ADC correction, sign=+1 for
// activations, -1 for weights) padded with zeros. Padded rows fully zeroed.
__global__ void quant_kernel(const float* __restrict__ in, int R, int C, int ldq,
                             const unsigned* __restrict__ slot, float sign,
                             u16* __restrict__ qout) {
  const int segs_per_row = C >> 8;
  const int seg = blockIdx.x * 4 + (threadIdx.x >> 6);
  const int lane = threadIdx.x & 63;
  const int r = seg / segs_per_row;
  const int s = seg - r * segs_per_row;
  const float scale = fmaxf(__uint_as_float(*slot) / 7.0f, 1e-8f);
  const size_t qbase = (size_t)r * ldq + (size_t)s * 256 + lane * 4;
  int mask = 0;
  if (r < R) {
    const size_t base = (size_t)r * C + (size_t)s * 256 + lane * 4;
    float4 v = *(const float4*)(in + base);
    int q0 = quant1(v.x, scale);
    int q1 = quant1(v.y, scale);
    int q2 = quant1(v.z, scale);
    int q3 = quant1(v.w, scale);
    u16x4 o;
    o[0] = (u16)(__float_as_uint((float)q0) >> 16);
    o[1] = (u16)(__float_as_uint((float)q1) >> 16);
    o[2] = (u16)(__float_as_uint((float)q2) >> 16);
    o[3] = (u16)(__float_as_uint((float)q3) >> 16);
    *(u16x4*)(qout + qbase) = o;
    mask = q0 & q1 & q2 & q3 & 15;
  } else {
    u16x4 z = {0, 0, 0, 0};
    *(u16x4*)(qout + qbase) = z;
    mask = 0;
  }
  for (int o = 32; o > 0; o >>= 1) mask &= __shfl_xor(mask, o);
  if (lane == 0) {
    float sv = sign * (float)((mask & 7) - (mask & 8));
    qout[(size_t)r * ldq + C + s] = (u16)(__float_as_uint(sv) >> 16);
  }
  if (s == 0 && lane < (32 - segs_per_row))
    qout[(size_t)r * ldq + C + segs_per_row + lane] = 0;
}

// out = partial * (s_h * s_w2) + b2  (exact same expression order as before)
__global__ void epi2_kernel(const float* __restrict__ partial,
                            const float* __restrict__ b2,
                            const unsigned* __restrict__ slots,
                            float* __restrict__ out, long n4) {
  const float sa = fmaxf(__uint_as_float(slots[3]) / 7.0f, 1e-8f);
  const float sb = fmaxf(__uint_as_float(slots[2]) / 7.0f, 1e-8f);
  const float sc = sa * sb;
  long i = (long)blockIdx.x * blockDim.x + threadIdx.x;
  const long stride = (long)gridDim.x * blockDim.x;
  for (; i < n4; i += stride) {
    float4 v = ((const float4*)partial)[i];
    float4 bb = ((const float4*)b2)[i % 192];  // 768/4
    float4 o;
    o.x = epi_scale(v.x, sc, bb.x);
    o.y = epi_scale(v.y, sc, bb.y);
    o.z = epi_scale(v.z, sc, bb.z);
    o.w = epi_scale(v.w, sc, bb.w);
    ((float4*)out)[i] = o;
  }
}

// ---------------- GEMM -------------------------------------------------------
// MODE 0: direct epilogue (scale+bias+gelu, store f32, fused absmax->slots[3])
// MODE 1: split-K, atomicAdd exact-integer partials (blockIdx.y = K-chunk)
// 128x128 tile, 4 waves, 16x16x32 bf16 MFMA, double-buffered LDS with counted
// vmcnt so the next tile's global_load_lds stays in flight across barriers.
template <int MODE>
__global__ __launch_bounds__(256) void gemm_cim(
    const u16* __restrict__ A, const u16* __restrict__ B,
    int Mstore, int ldq, int mtiles, int kbase, int krem,
    const unsigned* __restrict__ slots, int slotA, int slotB,
    const float* __restrict__ bias, float* __restrict__ outp, int ldo) {
  __shared__ u16 As[2][128 * 32];
  __shared__ u16 Bs[2][128 * 32];
  const int tid = threadIdx.x;
  const int lane = tid & 63;
  const int wv = tid >> 6;
  const int bm = blockIdx.x % mtiles;
  const int bn = blockIdx.x / mtiles;
  const long m0 = (long)bm * 128;
  const long n0 = (long)bn * 128;
  const int chunk = blockIdx.y;
  const int k_begin = chunk * kbase + min(chunk, krem);
  const int k_iters = kbase + (chunk < krem ? 1 : 0);

  const int off = wv * 1024 + lane * 16;  // this wave's 1KB slice of a 4KB chunk
  const int r0 = off >> 6;                // row 0..63
  const int cb = off & 63;                // byte within 64B k-slice
  const long rowb = (long)ldq * 2;
  const char* gA = (const char*)A + (m0 + r0) * rowb + (long)k_begin * 64 + cb;
  const char* gB = (const char*)B + (n0 + r0) * rowb + (long)k_begin * 64 + cb;

  const int wm = wv >> 1, wn = wv & 1;
  const int lr = lane & 15, kg = lane >> 4;

  f32x4 acc[4][4] = {};

#define STAGE(buf, kt) do { \
    const long kb = (long)(kt) * 64; \
    char* la = (char*)As[buf] + wv * 1024; \
    char* lb = (char*)Bs[buf] + wv * 1024; \
    GLL(gA + kb, la); \
    GLL(gA + 64 * rowb + kb, la + 4096); \
    GLL(gB + kb, lb); \
    GLL(gB + 64 * rowb + kb, lb + 4096); \
  } while (0)

  STAGE(0, 0);
  for (int kt = 0; kt < k_iters; ++kt) {
    const int cur = kt & 1;
    if (kt + 1 < k_iters) {
      STAGE(cur ^ 1, kt + 1);                          // prefetch next tile
      asm volatile("s_waitcnt vmcnt(4)" ::: "memory"); // wait only cur's 4 loads
    } else {
      asm volatile("s_waitcnt vmcnt(0)" ::: "memory");
    }
    __builtin_amdgcn_s_barrier();  // all waves' cur chunks landed in LDS
    s16x8 av[4], bv[4];
#pragma unroll
    for (int f = 0; f < 4; ++f)
      av[f] = *(const s16x8*)(As[cur] + (wm * 64 + f * 16 + lr) * 32 + kg * 8);
#pragma unroll
    for (int f = 0; f < 4; ++f)
      bv[f] = *(const s16x8*)(Bs[cur] + (wn * 64 + f * 16 + lr) * 32 + kg * 8);
#pragma unroll
    for (int fa = 0; fa < 4; ++fa)
#pragma unroll
      for (int fb = 0; fb < 4; ++fb)
        acc[fa][fb] = __builtin_amdgcn_mfma_f32_16x16x32_bf16(av[fa], bv[fb], acc[fa][fb], 0, 0, 0);
    __builtin_amdgcn_s_barrier();  // reads done before this buf is re-staged
  }
#undef STAGE

  if (MODE == 0) {
    const float sa = fmaxf(__uint_as_float(slots[slotA]) / 7.0f, 1e-8f);
    const float sb = fmaxf(__uint_as_float(slots[slotB]) / 7.0f, 1e-8f);
    const float sc = sa * sb;
    float hmax = 0.0f;
#pragma unroll
    for (int fa = 0; fa < 4; ++fa) {
#pragma unroll
      for (int r = 0; r < 4; ++r) {
        const long m = m0 + wm * 64 + fa * 16 + kg * 4 + r;  // row=(lane>>4)*4+reg
        if (m < Mstore) {
#pragma unroll
          for (int fb = 0; fb < 4; ++fb) {
            const long n = n0 + wn * 64 + fb * 16 + lr;      // col=lane&15
            float v = epi_scale(acc[fa][fb][r], sc, bias[n]);
            v = gelu_exact(v);
            outp[m * (long)ldo + n] = v;
            hmax = fmaxf(hmax, fabsf(v));
          }
        }
      }
    }
    for (int o = 32; o > 0; o >>= 1) hmax = fmaxf(hmax, __shfl_xor(hmax, o));
    if (lane == 0) atomicMax((unsigned*)slots + 3, __float_as_uint(hmax));
  } else {
#pragma unroll
    for (int fa = 0; fa < 4; ++fa) {
#pragma unroll
      for (int r = 0; r < 4; ++r) {
        const long m = m0 + wm * 64 + fa * 16 + kg * 4 + r;
        if (m < Mstore) {
#pragma unroll
          for (int fb = 0; fb < 4; ++fb) {
            const long n = n0 + wn * 64 + fb * 16 + lr;
            atomicAdd(outp + m * (long)ldo + n, acc[fa][fb][r]);  // exact ints
          }
        }
      }
    }
  }
}

// ---------------- launch -----------------------------------------------------

extern "C" void kernel_launch(void* const* d_in, const int* in_sizes, int n_in,
                              void* d_out, int out_size, void* d_ws, size_t ws_size,
                              hipStream_t stream) {
  const float* x  = (const float*)d_in[0];
  const float* w1 = (const float*)d_in[1];
  const float* b1 = (const float*)d_in[2];
  const float* w2 = (const float*)d_in[3];
  const float* b2 = (const float*)d_in[4];
  float* out = (float*)d_out;

  const int Ntok = 16 * 197;  // 3152
  const int Mpad = 3200;      // 25 tiles of 128
  const int D = 768, H = 3072;
  const int ldq1 = D + 32;    // 800  (25 k-iters of 32)
  const int ldq2 = H + 32;    // 3104 (97 k-iters of 32)

  char* ws = (char*)d_ws;
  size_t o = 0;
  unsigned* slots = (unsigned*)(ws + o); o += 256;  // [x, w1, w2, h]
  u16* xq  = (u16*)(ws + o); o += (size_t)Mpad * ldq1 * 2;
  u16* wq1 = (u16*)(ws + o); o += (size_t)H * ldq1 * 2;
  u16* wq2 = (u16*)(ws + o); o += (size_t)D * ldq2 * 2;
  u16* hq  = (u16*)(ws + o); o += (size_t)Mpad * ldq2 * 2;
  float* hbuf = (float*)(ws + o); o += (size_t)Ntok * H * 4;
  float* partial = (float*)(ws + o); o += (size_t)Ntok * D * 4;
  (void)ws_size; (void)in_sizes; (void)n_in; (void)out_size;

  hipLaunchKernelGGL(init_kernel, dim3(1), dim3(64), 0, stream, slots);

  hipLaunchKernelGGL(absmax3, dim3(512, 3), dim3(256), 0, stream,
                     x, (long)Ntok * D / 4, w1, (long)H * D / 4,
                     w2, (long)D * H / 4, slots);

  hipLaunchKernelGGL(quant_kernel, dim3(Mpad * (D / 256) / 4), dim3(256), 0, stream,
                     x, Ntok, D, ldq1, slots + 0, 1.0f, xq);
  hipLaunchKernelGGL(quant_kernel, dim3(H * (D / 256) / 4), dim3(256), 0, stream,
                     w1, H, D, ldq1, slots + 1, -1.0f, wq1);
  hipLaunchKernelGGL(quant_kernel, dim3(D * (H / 256) / 4), dim3(256), 0, stream,
                     w2, D, H, ldq2, slots + 2, -1.0f, wq2);

  hipMemsetAsync(partial, 0, (size_t)Ntok * D * 4, stream);

  // layer 1: h = gelu(cim(x,w1) + b1), fused absmax(h) -> slots[3]
  hipLaunchKernelGGL((gemm_cim<0>), dim3((Mpad / 128) * (H / 128), 1), dim3(256), 0, stream,
                     xq, wq1, Ntok, ldq1, Mpad / 128, ldq1 / 32, 0,
                     slots, 0, 1, b1, hbuf, H);

  hipLaunchKernelGGL(quant_kernel, dim3(Mpad * (H / 256) / 4), dim3(256), 0, stream,
                     hbuf, Ntok, H, ldq2, slots + 3, 1.0f, hq);

  // layer 2: split-K x4, exact integer partials
  hipLaunchKernelGGL((gemm_cim<1>), dim3((Mpad / 128) * (D / 128), 4), dim3(256), 0, stream,
                     hq, wq2, Ntok, ldq2, Mpad / 128, (ldq2 / 32) / 4, (ldq2 / 32) % 4,
                     slots, 0, 0, nullptr, partial, D);

  hipLaunchKernelGGL(epi2_kernel, dim3(512), dim3(256), 0, stream,
                     partial, b2, slots, out, (long)Ntok * D / 4);
}